// Round 2
// baseline (666.684 us; speedup 1.0000x reference)
//
#include <hip/hip_runtime.h>
#include <hip/hip_bf16.h>

// Fused GRU-like cell: 200000 rows, IN=HID=256, fp32 in/out, bf16 MFMA compute.
// Kernel 1 (wconv): convert weights fp32->bf16 into d_ws, fragment-packed per
//                   MFMA B-operand tile; combine biases.
// Kernel 2 (gru):   per-block 64 rows, fully fused 6-stage MFMA pipeline.
//                   LDS = 64 KB (cbuf aliases the dead x-region) -> 2 blocks/CU.

typedef short bf16x8 __attribute__((ext_vector_type(8)));   // 8 bf16 = 4 VGPRs
typedef float f32x4  __attribute__((ext_vector_type(4)));

__device__ __forceinline__ unsigned int rne_bf16(float f) {
  unsigned int u = __builtin_bit_cast(unsigned int, f);
  return (u + 0x7fffu + ((u >> 16) & 1u)) >> 16;
}
__device__ __forceinline__ unsigned int pack2(float a, float b) {
  return rne_bf16(a) | (rne_bf16(b) << 16);
}
__device__ __forceinline__ float bf2f(unsigned short s) {
  unsigned int u = ((unsigned int)s) << 16;
  return __builtin_bit_cast(float, u);
}

// ws layout (bf16 shorts), fragment-packed: frag f holds 8 bf16 for lane=f&63
// of tile (nt, kt):  f = (nt*KT + kt)*64 + lane,  n = nt*16+(lane&15),
// k = kt*32+(lane>>4)*8.  Matrix bases (frags): Bz 0, Br 16384, Wh 32768,
// Uh 40960, G 49152, L 57344.  fp32 biases at byte 1048576.
__global__ void wconv_kernel(const float* Wz, const float* Uz, const float* Wr, const float* Ur,
                             const float* Wh, const float* Uh, const float* G, const float* L,
                             const float* bWz, const float* bUz, const float* bWr, const float* bUr,
                             const float* bWh, const float* bUh, const float* bG, const float* bL,
                             const float* bias_h,
                             unsigned short* wb, float* bout) {
  int f = blockIdx.x * blockDim.x + threadIdx.x;   // 65536 fragments
  const float* A; const float* B = nullptr;
  int rel, K;
  if (f < 16384)      { A = Wz; B = Uz; rel = f;         K = 512; }
  else if (f < 32768) { A = Wr; B = Ur; rel = f - 16384; K = 512; }
  else {
    int m = (f - 32768) >> 13; rel = (f - 32768) & 8191; K = 256;
    const float* mats[4] = {Wh, Uh, G, L};
    A = mats[m];
  }
  int lane = rel & 63, tile = rel >> 6;
  int KT = K >> 5;                       // 16 or 8
  int kt = tile & (KT - 1), nt = tile >> (K == 512 ? 4 : 3);
  int n = nt * 16 + (lane & 15);
  int k0 = kt * 32 + (lane >> 4) * 8;
  unsigned short tmp[8];
#pragma unroll
  for (int j = 0; j < 8; ++j) {
    int k = k0 + j;
    float v = (k < 256) ? A[n * 256 + k] : B[n * 256 + (k - 256)];
    tmp[j] = (unsigned short)rne_bf16(v);
  }
  *reinterpret_cast<uint4*>(wb + (size_t)f * 8) = *reinterpret_cast<const uint4*>(tmp);

  if (f < 256) {
    bout[f]        = bWz[f] + bUz[f];
    bout[256 + f]  = bWr[f] + bUr[f];
    bout[512 + f]  = bWh[f] + bUh[f] + bias_h[f];
    bout[768 + f]  = bG[f];
    bout[1024 + f] = bL[f];
  }
}

// Main fused kernel. 512 threads (8 waves). BM=64 rows/block.
// Wave w owns output cols [32w, 32w+32). MFMA 16x16x32 bf16.
// LDS xh[64][512] bf16, XOR-swizzled 16B chunks: chunks 0..31 hold x
// (reused as cbuf after phase 1), chunks 32..63 hold h.
__global__ __launch_bounds__(512, 4) void gru_kernel(
    const float* __restrict__ x, const float* __restrict__ h,
    const unsigned short* __restrict__ wb,
    const float* __restrict__ bia,
    float* __restrict__ out)
{
  __shared__ unsigned short xh[64 * 512];    // 64 KB total

  const int tid  = threadIdx.x;
  const int lane = tid & 63;
  const int wave = tid >> 6;
  const int q    = lane >> 4;     // quarter-wave id
  const int lr   = lane & 15;
  const long row0 = (long)blockIdx.x * 64;

  // ---------------- Phase 0: stage x,h -> LDS bf16 (swizzled) ----------------
#pragma unroll
  for (int i = 0; i < 4; ++i) {
    int c = tid + i * 512;               // chunk id: 64 rows x 32 chunks
    int r = c >> 5, c8 = c & 31;
    const float4* p = reinterpret_cast<const float4*>(x + (row0 + r) * 256 + c8 * 8);
    float4 v0 = p[0], v1 = p[1];
    uint4 w;
    w.x = pack2(v0.x, v0.y); w.y = pack2(v0.z, v0.w);
    w.z = pack2(v1.x, v1.y); w.w = pack2(v1.z, v1.w);
    reinterpret_cast<uint4*>(xh)[r * 64 + (c8 ^ (r & 7))] = w;
  }
#pragma unroll
  for (int i = 0; i < 4; ++i) {
    int c = tid + i * 512;
    int r = c >> 5, c8 = c & 31;
    const float4* p = reinterpret_cast<const float4*>(h + (row0 + r) * 256 + c8 * 8);
    float4 v0 = p[0], v1 = p[1];
    uint4 w;
    w.x = pack2(v0.x, v0.y); w.y = pack2(v0.z, v0.w);
    w.z = pack2(v1.x, v1.y); w.w = pack2(v1.z, v1.w);
    reinterpret_cast<uint4*>(xh)[r * 64 + ((32 + c8) ^ (r & 7))] = w;
  }
  __syncthreads();

  const unsigned short* Bz = wb;                    // frag bases * 8 shorts
  const unsigned short* Br = wb + 131072;
  const unsigned short* Wh = wb + 262144;
  const unsigned short* Uh = wb + 327680;
  const unsigned short* Gw = wb + 393216;
  const unsigned short* Lw = wb + 458752;

  auto ldsA = [&](int mt, int ks) -> bf16x8 {  // x|h region (chunks 0..63)
    int r = mt * 16 + lr;
    int kc = ks * 4 + q;
    return reinterpret_cast<const bf16x8*>(xh)[r * 64 + (kc ^ (r & 7))];
  };
  auto ldsC = [&](int mt, int ks) -> bf16x8 {  // cbuf alias (chunks 0..31)
    int r = mt * 16 + lr;
    int kc = ks * 4 + q;
    return reinterpret_cast<const bf16x8*>(xh)[r * 64 + (kc ^ (r & 7))];
  };
  auto ldB = [&](const unsigned short* base, int KT, int ct, int ks) -> bf16x8 {
    int nt = wave * 2 + ct;
    return reinterpret_cast<const bf16x8*>(base)[(nt * KT + ks) * 64 + lane];
  };

  // ---------------- Phase 1: z, r (K=512) and x@Wh^T (K=256) ----------------
  f32x4 az[4][2] = {}; f32x4 ar[4][2] = {}; f32x4 ac[4][2] = {};

#pragma unroll 2
  for (int ks = 0; ks < 16; ++ks) {
    bf16x8 a[4];
#pragma unroll
    for (int mt = 0; mt < 4; ++mt) a[mt] = ldsA(mt, ks);
#pragma unroll
    for (int ct = 0; ct < 2; ++ct) {
      bf16x8 b = ldB(Bz, 16, ct, ks);
#pragma unroll
      for (int mt = 0; mt < 4; ++mt)
        az[mt][ct] = __builtin_amdgcn_mfma_f32_16x16x32_bf16(a[mt], b, az[mt][ct], 0, 0, 0);
    }
#pragma unroll
    for (int ct = 0; ct < 2; ++ct) {
      bf16x8 b = ldB(Br, 16, ct, ks);
#pragma unroll
      for (int mt = 0; mt < 4; ++mt)
        ar[mt][ct] = __builtin_amdgcn_mfma_f32_16x16x32_bf16(a[mt], b, ar[mt][ct], 0, 0, 0);
    }
    if (ks < 8) {  // x region only (k < 256)
#pragma unroll
      for (int ct = 0; ct < 2; ++ct) {
        bf16x8 b = ldB(Wh, 8, ct, ks);
#pragma unroll
        for (int mt = 0; mt < 4; ++mt)
          ac[mt][ct] = __builtin_amdgcn_mfma_f32_16x16x32_bf16(a[mt], b, ac[mt][ct], 0, 0, 0);
      }
    }
  }
  __syncthreads();   // everyone done reading x before cbuf overwrites it

  const int col0 = wave * 32 + lr;      // ct=0 column
  // z = sigmoid(.); r = sigmoid(.); rh = r*h -> cbuf (x region, bf16)
#pragma unroll
  for (int mt = 0; mt < 4; ++mt) {
#pragma unroll
    for (int ct = 0; ct < 2; ++ct) {
      int cg = col0 + ct * 16;
      float bzc = bia[cg];
      float brc = bia[256 + cg];
#pragma unroll
      for (int i = 0; i < 4; ++i) {
        int rl = mt * 16 + q * 4 + i;
        float zp = az[mt][ct][i] + bzc;
        az[mt][ct][i] = 1.f / (1.f + __expf(-zp));      // keep z in regs
        float rp = ar[mt][ct][i] + brc;
        float rv = 1.f / (1.f + __expf(-rp));
        int hc = 32 + (cg >> 3);
        float hval = bf2f(xh[rl * 512 + (hc ^ (rl & 7)) * 8 + (cg & 7)]);
        float rh = rv * hval;
        xh[rl * 512 + (((cg >> 3) ^ (rl & 7)) * 8) + (cg & 7)] = (unsigned short)rne_bf16(rh);
      }
    }
  }
  __syncthreads();

  // ---------------- Phase 2: cand += rh @ Uh^T (K=256) ----------------
#pragma unroll 2
  for (int ks = 0; ks < 8; ++ks) {
    bf16x8 a[4];
#pragma unroll
    for (int mt = 0; mt < 4; ++mt) a[mt] = ldsC(mt, ks);
#pragma unroll
    for (int ct = 0; ct < 2; ++ct) {
      bf16x8 b = ldB(Uh, 8, ct, ks);
#pragma unroll
      for (int mt = 0; mt < 4; ++mt)
        ac[mt][ct] = __builtin_amdgcn_mfma_f32_16x16x32_bf16(a[mt], b, ac[mt][ct], 0, 0, 0);
    }
  }
  __syncthreads();   // all reads of rh done before overwrite

  // cand = ac + bias; write bf16 into cbuf
#pragma unroll
  for (int mt = 0; mt < 4; ++mt) {
#pragma unroll
    for (int ct = 0; ct < 2; ++ct) {
      int cg = col0 + ct * 16;
      float bcc = bia[512 + cg];
#pragma unroll
      for (int i = 0; i < 4; ++i) {
        int rl = mt * 16 + q * 4 + i;
        float cd = ac[mt][ct][i] + bcc;
        xh[rl * 512 + (((cg >> 3) ^ (rl & 7)) * 8) + (cg & 7)] = (unsigned short)rne_bf16(cd);
      }
    }
  }
  __syncthreads();

  // ---------------- Phase 3: gate & linear (K=256 each) ----------------
  f32x4 ag[4][2] = {}; f32x4 al[4][2] = {};
#pragma unroll 2
  for (int ks = 0; ks < 8; ++ks) {
    bf16x8 a[4];
#pragma unroll
    for (int mt = 0; mt < 4; ++mt) a[mt] = ldsC(mt, ks);
#pragma unroll
    for (int ct = 0; ct < 2; ++ct) {
      bf16x8 b = ldB(Gw, 8, ct, ks);
#pragma unroll
      for (int mt = 0; mt < 4; ++mt)
        ag[mt][ct] = __builtin_amdgcn_mfma_f32_16x16x32_bf16(a[mt], b, ag[mt][ct], 0, 0, 0);
    }
#pragma unroll
    for (int ct = 0; ct < 2; ++ct) {
      bf16x8 b = ldB(Lw, 8, ct, ks);
#pragma unroll
      for (int mt = 0; mt < 4; ++mt)
        al[mt][ct] = __builtin_amdgcn_mfma_f32_16x16x32_bf16(a[mt], b, al[mt][ct], 0, 0, 0);
    }
  }

  // ---------------- Phase 4: epilogue ----------------
#pragma unroll
  for (int mt = 0; mt < 4; ++mt) {
#pragma unroll
    for (int ct = 0; ct < 2; ++ct) {
      int cg = col0 + ct * 16;
      float bgc = bia[768 + cg];
      float blc = bia[1024 + cg];
#pragma unroll
      for (int i = 0; i < 4; ++i) {
        int rl = mt * 16 + q * 4 + i;
        float gv = 1.f / (1.f + __expf(-(ag[mt][ct][i] + bgc)));
        float lv = al[mt][ct][i] + blc;
        float cand = lv * gv;
        int hc = 32 + (cg >> 3);
        float hval = bf2f(xh[rl * 512 + (hc ^ (rl & 7)) * 8 + (cg & 7)]);
        float zv = az[mt][ct][i];
        out[(row0 + rl) * 256 + cg] = zv * cand + (1.f - zv) * hval;
      }
    }
  }
}

extern "C" void kernel_launch(void* const* d_in, const int* in_sizes, int n_in,
                              void* d_out, int out_size, void* d_ws, size_t ws_size,
                              hipStream_t stream) {
  const float* x   = (const float*)d_in[0];
  const float* h   = (const float*)d_in[1];
  const float* Wz  = (const float*)d_in[2];  const float* bWz = (const float*)d_in[3];
  const float* Uz  = (const float*)d_in[4];  const float* bUz = (const float*)d_in[5];
  const float* Wr  = (const float*)d_in[6];  const float* bWr = (const float*)d_in[7];
  const float* Ur  = (const float*)d_in[8];  const float* bUr = (const float*)d_in[9];
  const float* Wh  = (const float*)d_in[10]; const float* bWh = (const float*)d_in[11];
  const float* Uh  = (const float*)d_in[12]; const float* bUh = (const float*)d_in[13];
  const float* G   = (const float*)d_in[14]; const float* bG  = (const float*)d_in[15];
  const float* L   = (const float*)d_in[16]; const float* bL  = (const float*)d_in[17];
  const float* bh  = (const float*)d_in[18];

  unsigned short* wb = (unsigned short*)d_ws;
  float* bia = (float*)((char*)d_ws + 1048576);

  wconv_kernel<<<256, 256, 0, stream>>>(Wz, Uz, Wr, Ur, Wh, Uh, G, L,
                                        bWz, bUz, bWr, bUr, bWh, bUh, bG, bL, bh,
                                        wb, bia);

  int rows = in_sizes[0] / 256;        // 200000
  int grid = rows / 64;                // 3125 (exact)
  gru_kernel<<<grid, 512, 0, stream>>>(x, h, wb, bia, (float*)d_out);
}

// Round 3
// 525.418 us; speedup vs baseline: 1.2689x; 1.2689x over previous
//
#include <hip/hip_runtime.h>
#include <hip/hip_bf16.h>

// Fused GRU-like cell: 200000 rows, IN=HID=256, fp32 in/out, bf16 MFMA compute.
// Kernel 1 (wconv): convert weights fp32->bf16 into d_ws, fragment-packed per
//                   MFMA B-operand tile; combine biases.
// Kernel 2 (gru):   per-block 64 rows, phase-split register-disciplined
//                   pipeline; LDS = 64 KB -> 2 blocks/CU, no spills.

typedef short bf16x8 __attribute__((ext_vector_type(8)));   // 8 bf16 = 4 VGPRs
typedef float f32x4  __attribute__((ext_vector_type(4)));

__device__ __forceinline__ unsigned int rne_bf16(float f) {
  unsigned int u = __builtin_bit_cast(unsigned int, f);
  return (u + 0x7fffu + ((u >> 16) & 1u)) >> 16;
}
__device__ __forceinline__ unsigned int pack2(float a, float b) {
  return rne_bf16(a) | (rne_bf16(b) << 16);
}
__device__ __forceinline__ float bf2f(unsigned short s) {
  unsigned int u = ((unsigned int)s) << 16;
  return __builtin_bit_cast(float, u);
}
__device__ __forceinline__ float sigmoidf_(float v) {
  return 1.f / (1.f + __expf(-v));
}

// ws layout (bf16 shorts), fragment-packed: frag f holds 8 bf16 for lane=f&63
// of tile (nt, kt):  f = (nt*KT + kt)*64 + lane,  n = nt*16+(lane&15),
// k = kt*32+(lane>>4)*8.  Matrix bases (frags): Bz 0, Br 16384, Wh 32768,
// Uh 40960, G 49152, L 57344.  fp32 biases at byte 1048576.
__global__ void wconv_kernel(const float* Wz, const float* Uz, const float* Wr, const float* Ur,
                             const float* Wh, const float* Uh, const float* G, const float* L,
                             const float* bWz, const float* bUz, const float* bWr, const float* bUr,
                             const float* bWh, const float* bUh, const float* bG, const float* bL,
                             const float* bias_h,
                             unsigned short* wb, float* bout) {
  int f = blockIdx.x * blockDim.x + threadIdx.x;   // 65536 fragments
  const float* A; const float* B = nullptr;
  int rel, K;
  if (f < 16384)      { A = Wz; B = Uz; rel = f;         K = 512; }
  else if (f < 32768) { A = Wr; B = Ur; rel = f - 16384; K = 512; }
  else {
    int m = (f - 32768) >> 13; rel = (f - 32768) & 8191; K = 256;
    const float* mats[4] = {Wh, Uh, G, L};
    A = mats[m];
  }
  int lane = rel & 63, tile = rel >> 6;
  int KT = K >> 5;                       // 16 or 8
  int kt = tile & (KT - 1), nt = tile >> (K == 512 ? 4 : 3);
  int n = nt * 16 + (lane & 15);
  int k0 = kt * 32 + (lane >> 4) * 8;
  unsigned short tmp[8];
#pragma unroll
  for (int j = 0; j < 8; ++j) {
    int k = k0 + j;
    float v = (k < 256) ? A[n * 256 + k] : B[n * 256 + (k - 256)];
    tmp[j] = (unsigned short)rne_bf16(v);
  }
  *reinterpret_cast<uint4*>(wb + (size_t)f * 8) = *reinterpret_cast<const uint4*>(tmp);

  if (f < 256) {
    bout[f]        = bWz[f] + bUz[f];
    bout[256 + f]  = bWr[f] + bUr[f];
    bout[512 + f]  = bWh[f] + bUh[f] + bias_h[f];
    bout[768 + f]  = bG[f];
    bout[1024 + f] = bL[f];
  }
}

// Main fused kernel. 512 threads (8 waves). BM=64 rows/block.
// Wave w owns output cols [32w, 32w+32). MFMA 16x16x32 bf16.
// LDS xh[64][512] bf16, XOR-swizzled 16B chunks: chunks 0..31 hold x
// (reused for rh then cand after phase 2), chunks 32..63 hold h.
__global__ __launch_bounds__(512, 4) void gru_kernel(
    const float* __restrict__ x, const float* __restrict__ h,
    const unsigned short* __restrict__ wb,
    const float* __restrict__ bia,
    float* __restrict__ out)
{
  __shared__ unsigned short xh[64 * 512];    // 64 KB total

  const int tid  = threadIdx.x;
  const int lane = tid & 63;
  const int wave = tid >> 6;
  const int q    = lane >> 4;     // quarter-wave id
  const int lr   = lane & 15;
  const long row0 = (long)blockIdx.x * 64;

  // ---------------- Phase 0: stage x,h -> LDS bf16 (swizzled) ----------------
#pragma unroll
  for (int i = 0; i < 4; ++i) {
    int c = tid + i * 512;               // chunk id: 64 rows x 32 chunks
    int r = c >> 5, c8 = c & 31;
    const float4* p = reinterpret_cast<const float4*>(x + (row0 + r) * 256 + c8 * 8);
    float4 v0 = p[0], v1 = p[1];
    uint4 w;
    w.x = pack2(v0.x, v0.y); w.y = pack2(v0.z, v0.w);
    w.z = pack2(v1.x, v1.y); w.w = pack2(v1.z, v1.w);
    reinterpret_cast<uint4*>(xh)[r * 64 + (c8 ^ (r & 7))] = w;
  }
#pragma unroll
  for (int i = 0; i < 4; ++i) {
    int c = tid + i * 512;
    int r = c >> 5, c8 = c & 31;
    const float4* p = reinterpret_cast<const float4*>(h + (row0 + r) * 256 + c8 * 8);
    float4 v0 = p[0], v1 = p[1];
    uint4 w;
    w.x = pack2(v0.x, v0.y); w.y = pack2(v0.z, v0.w);
    w.z = pack2(v1.x, v1.y); w.w = pack2(v1.z, v1.w);
    reinterpret_cast<uint4*>(xh)[r * 64 + ((32 + c8) ^ (r & 7))] = w;
  }
  __syncthreads();

  const unsigned short* Bz = wb;                    // frag-packed bases
  const unsigned short* Br = wb + 131072;
  const unsigned short* Wh = wb + 262144;
  const unsigned short* Uh = wb + 327680;
  const unsigned short* Gw = wb + 393216;
  const unsigned short* Lw = wb + 458752;

  auto ldsA = [&](int mt, int ks) -> bf16x8 {  // A frag from xh (chunk ks*4+q)
    int r = mt * 16 + lr;
    int kc = ks * 4 + q;
    return reinterpret_cast<const bf16x8*>(xh)[r * 64 + (kc ^ (r & 7))];
  };
  auto ldB = [&](const unsigned short* base, int KT, int ct, int ks) -> bf16x8 {
    int nt = wave * 2 + ct;
    return reinterpret_cast<const bf16x8*>(base)[(nt * KT + ks) * 64 + lane];
  };

  const int col0 = wave * 32 + lr;      // ct=0 column

  // ---------------- Phase 1: z, r (K=512) ----------------
  unsigned int zpk[16], rhpk[16];
  {
    f32x4 az[4][2] = {}; f32x4 ar[4][2] = {};
#pragma unroll 2
    for (int ks = 0; ks < 16; ++ks) {
      bf16x8 bz0 = ldB(Bz, 16, 0, ks), bz1 = ldB(Bz, 16, 1, ks);
      bf16x8 br0 = ldB(Br, 16, 0, ks), br1 = ldB(Br, 16, 1, ks);
#pragma unroll
      for (int mt = 0; mt < 4; ++mt) {
        bf16x8 a = ldsA(mt, ks);
        az[mt][0] = __builtin_amdgcn_mfma_f32_16x16x32_bf16(a, bz0, az[mt][0], 0, 0, 0);
        az[mt][1] = __builtin_amdgcn_mfma_f32_16x16x32_bf16(a, bz1, az[mt][1], 0, 0, 0);
        ar[mt][0] = __builtin_amdgcn_mfma_f32_16x16x32_bf16(a, br0, ar[mt][0], 0, 0, 0);
        ar[mt][1] = __builtin_amdgcn_mfma_f32_16x16x32_bf16(a, br1, ar[mt][1], 0, 0, 0);
      }
    }
    // sigmoid; pack z and r*h to bf16 pairs (rows 2ii, 2ii+1)
#pragma unroll
    for (int mt = 0; mt < 4; ++mt) {
#pragma unroll
      for (int ct = 0; ct < 2; ++ct) {
        int cg = col0 + ct * 16;
        float bzc = bia[cg];
        float brc = bia[256 + cg];
        int hc = 32 + (cg >> 3);
#pragma unroll
        for (int ii = 0; ii < 2; ++ii) {
          int rl0 = mt * 16 + q * 4 + 2 * ii;
          float z0 = sigmoidf_(az[mt][ct][2 * ii]     + bzc);
          float z1 = sigmoidf_(az[mt][ct][2 * ii + 1] + bzc);
          zpk[(mt * 2 + ct) * 2 + ii] = pack2(z0, z1);
          float r0 = sigmoidf_(ar[mt][ct][2 * ii]     + brc);
          float r1 = sigmoidf_(ar[mt][ct][2 * ii + 1] + brc);
          float h0 = bf2f(xh[rl0 * 512       + (hc ^ (rl0 & 7))       * 8 + (cg & 7)]);
          float h1 = bf2f(xh[(rl0 + 1) * 512 + (hc ^ ((rl0 + 1) & 7)) * 8 + (cg & 7)]);
          rhpk[(mt * 2 + ct) * 2 + ii] = pack2(r0 * h0, r1 * h1);
        }
      }
    }
  }

  // ---------------- Phase 2: ac = x @ Wh^T (K=256, x region) ----------------
  f32x4 ac[4][2] = {};
#pragma unroll 2
  for (int ks = 0; ks < 8; ++ks) {
    bf16x8 b0 = ldB(Wh, 8, 0, ks), b1 = ldB(Wh, 8, 1, ks);
#pragma unroll
    for (int mt = 0; mt < 4; ++mt) {
      bf16x8 a = ldsA(mt, ks);
      ac[mt][0] = __builtin_amdgcn_mfma_f32_16x16x32_bf16(a, b0, ac[mt][0], 0, 0, 0);
      ac[mt][1] = __builtin_amdgcn_mfma_f32_16x16x32_bf16(a, b1, ac[mt][1], 0, 0, 0);
    }
  }
  __syncthreads();   // all waves done reading x

  // write rh (bf16 bits straight from rhpk) into the x region
#pragma unroll
  for (int mt = 0; mt < 4; ++mt) {
#pragma unroll
    for (int ct = 0; ct < 2; ++ct) {
      int cg = col0 + ct * 16;
#pragma unroll
      for (int ii = 0; ii < 2; ++ii) {
        unsigned int v = rhpk[(mt * 2 + ct) * 2 + ii];
        int rl0 = mt * 16 + q * 4 + 2 * ii;
        xh[rl0 * 512       + (((cg >> 3) ^ (rl0 & 7))       * 8) + (cg & 7)] = (unsigned short)(v & 0xffffu);
        xh[(rl0 + 1) * 512 + (((cg >> 3) ^ ((rl0 + 1) & 7)) * 8) + (cg & 7)] = (unsigned short)(v >> 16);
      }
    }
  }
  __syncthreads();

  // ---------------- Phase 3: ac += rh @ Uh^T (K=256) ----------------
#pragma unroll 2
  for (int ks = 0; ks < 8; ++ks) {
    bf16x8 b0 = ldB(Uh, 8, 0, ks), b1 = ldB(Uh, 8, 1, ks);
#pragma unroll
    for (int mt = 0; mt < 4; ++mt) {
      bf16x8 a = ldsA(mt, ks);
      ac[mt][0] = __builtin_amdgcn_mfma_f32_16x16x32_bf16(a, b0, ac[mt][0], 0, 0, 0);
      ac[mt][1] = __builtin_amdgcn_mfma_f32_16x16x32_bf16(a, b1, ac[mt][1], 0, 0, 0);
    }
  }
  __syncthreads();   // all reads of rh done before overwrite

  // cand = ac + bias -> bf16 into same region
#pragma unroll
  for (int mt = 0; mt < 4; ++mt) {
#pragma unroll
    for (int ct = 0; ct < 2; ++ct) {
      int cg = col0 + ct * 16;
      float bcc = bia[512 + cg];
#pragma unroll
      for (int i = 0; i < 4; ++i) {
        int rl = mt * 16 + q * 4 + i;
        float cd = ac[mt][ct][i] + bcc;
        xh[rl * 512 + (((cg >> 3) ^ (rl & 7)) * 8) + (cg & 7)] = (unsigned short)rne_bf16(cd);
      }
    }
  }
  __syncthreads();

  // ---------------- Phase 4: gate & linear (K=256 each) ----------------
  f32x4 ag[4][2] = {}; f32x4 al[4][2] = {};
#pragma unroll 2
  for (int ks = 0; ks < 8; ++ks) {
    bf16x8 bg0 = ldB(Gw, 8, 0, ks), bg1 = ldB(Gw, 8, 1, ks);
    bf16x8 bl0 = ldB(Lw, 8, 0, ks), bl1 = ldB(Lw, 8, 1, ks);
#pragma unroll
    for (int mt = 0; mt < 4; ++mt) {
      bf16x8 a = ldsA(mt, ks);
      ag[mt][0] = __builtin_amdgcn_mfma_f32_16x16x32_bf16(a, bg0, ag[mt][0], 0, 0, 0);
      ag[mt][1] = __builtin_amdgcn_mfma_f32_16x16x32_bf16(a, bg1, ag[mt][1], 0, 0, 0);
      al[mt][0] = __builtin_amdgcn_mfma_f32_16x16x32_bf16(a, bl0, al[mt][0], 0, 0, 0);
      al[mt][1] = __builtin_amdgcn_mfma_f32_16x16x32_bf16(a, bl1, al[mt][1], 0, 0, 0);
    }
  }

  // ---------------- Phase 5: epilogue ----------------
#pragma unroll
  for (int mt = 0; mt < 4; ++mt) {
#pragma unroll
    for (int ct = 0; ct < 2; ++ct) {
      int cg = col0 + ct * 16;
      float bgc = bia[768 + cg];
      float blc = bia[1024 + cg];
      int hc = 32 + (cg >> 3);
#pragma unroll
      for (int ii = 0; ii < 2; ++ii) {
        unsigned int zp = zpk[(mt * 2 + ct) * 2 + ii];
#pragma unroll
        for (int j = 0; j < 2; ++j) {
          int i = 2 * ii + j;
          int rl = mt * 16 + q * 4 + i;
          float gv = sigmoidf_(ag[mt][ct][i] + bgc);
          float lv = al[mt][ct][i] + blc;
          float cand = lv * gv;
          float zv = bf2f((unsigned short)(j == 0 ? (zp & 0xffffu) : (zp >> 16)));
          float hval = bf2f(xh[rl * 512 + (hc ^ (rl & 7)) * 8 + (cg & 7)]);
          out[(row0 + rl) * 256 + cg] = zv * cand + (1.f - zv) * hval;
        }
      }
    }
  }
}

extern "C" void kernel_launch(void* const* d_in, const int* in_sizes, int n_in,
                              void* d_out, int out_size, void* d_ws, size_t ws_size,
                              hipStream_t stream) {
  const float* x   = (const float*)d_in[0];
  const float* h   = (const float*)d_in[1];
  const float* Wz  = (const float*)d_in[2];  const float* bWz = (const float*)d_in[3];
  const float* Uz  = (const float*)d_in[4];  const float* bUz = (const float*)d_in[5];
  const float* Wr  = (const float*)d_in[6];  const float* bWr = (const float*)d_in[7];
  const float* Ur  = (const float*)d_in[8];  const float* bUr = (const float*)d_in[9];
  const float* Wh  = (const float*)d_in[10]; const float* bWh = (const float*)d_in[11];
  const float* Uh  = (const float*)d_in[12]; const float* bUh = (const float*)d_in[13];
  const float* G   = (const float*)d_in[14]; const float* bG  = (const float*)d_in[15];
  const float* L   = (const float*)d_in[16]; const float* bL  = (const float*)d_in[17];
  const float* bh  = (const float*)d_in[18];

  unsigned short* wb = (unsigned short*)d_ws;
  float* bia = (float*)((char*)d_ws + 1048576);

  wconv_kernel<<<256, 256, 0, stream>>>(Wz, Uz, Wr, Ur, Wh, Uh, G, L,
                                        bWz, bUz, bWr, bUr, bWh, bUh, bG, bL, bh,
                                        wb, bia);

  int rows = in_sizes[0] / 256;        // 200000
  int grid = rows / 64;                // 3125 (exact)
  gru_kernel<<<grid, 512, 0, stream>>>(x, h, wb, bia, (float*)d_out);
}